// Round 3
// baseline (381.071 us; speedup 1.0000x reference)
//
#include <hip/hip_runtime.h>
#include <hip/hip_bf16.h>

#define N_NODES 50000
#define N_EDGES 800000
#define IN_F 256
#define NH 4
#define DH 64
#define HD 256
#define ALPHA 0.2f

typedef short bf16x8 __attribute__((ext_vector_type(8)));
typedef float f32x4 __attribute__((ext_vector_type(4)));

__device__ __forceinline__ unsigned short f2bf(float f) {
    unsigned u = __float_as_uint(f);
    u = (u + 0x7FFFu + ((u >> 16) & 1u)) >> 16;   // RNE
    return (unsigned short)u;
}
__device__ __forceinline__ float bf2f(unsigned short h) {
    return __uint_as_float(((unsigned)h) << 16);
}

// ---------------- fc_w [k][n] fp32 -> Bt [n][k] bf16 (transpose + convert) ----------
__global__ __launch_bounds__(256) void k_cvt_w(const float* __restrict__ fw,
                                               unsigned short* __restrict__ Bt) {
    int n = blockIdx.x;            // 0..255
    int k = threadIdx.x;           // 0..255
    Bt[n * 256 + k] = f2bf(fw[k * 256 + n]);
}

// ---------------- GEMM: ftb = bf16( feat @ fc_w ) + fused el/er ----------------
// BM=128, BN=256 (full), 512 threads = 8 waves as 2M x 4N; each wave's 64-col slice = one head
__global__ __launch_bounds__(512) void k_gemm(const float* __restrict__ A,
                                              const unsigned short* __restrict__ Bt,
                                              unsigned short* __restrict__ ftb,
                                              float* __restrict__ el,
                                              float* __restrict__ er,
                                              const float* __restrict__ al,
                                              const float* __restrict__ ar, int M) {
    __shared__ __align__(16) char smem[131072];   // B-tile 256x256 bf16 (swizzled); reused as 64x257 f32 x2 phases
    const int tid = threadIdx.x;
    const int m0 = blockIdx.x * 128;

    // stage full B [256][256] bf16, lane-contiguous global reads, XOR-swizzled LDS
    #pragma unroll
    for (int c = 0; c < 16; c++) {
        int o = c * 8192 + tid * 16;            // byte offset, 131072 total
        bf16x8 v = *(const bf16x8*)((const char*)Bt + o);
        int nl = o >> 9;
        int lb = o ^ ((nl & 7) << 4);
        *(bf16x8*)(smem + lb) = v;
    }
    __syncthreads();

    const int w = tid >> 6, lane = tid & 63;
    const int wm = w >> 2, wn = w & 3;          // 2 x 4
    const int fr = lane & 15, quad = lane >> 4;

    const float* arow[4];
    int grow[4];
    #pragma unroll
    for (int j = 0; j < 4; j++) {
        grow[j] = m0 + wm * 64 + j * 16 + fr;
        int cr = grow[j] < M ? grow[j] : (M - 1);
        arow[j] = A + (size_t)cr * IN_F;
    }

    f32x4 acc[4][4];
    #pragma unroll
    for (int j = 0; j < 4; j++)
        #pragma unroll
        for (int f = 0; f < 4; f++) acc[j][f] = (f32x4){0.f, 0.f, 0.f, 0.f};

    #pragma unroll
    for (int kk = 0; kk < 8; kk++) {
        bf16x8 af[4];
        #pragma unroll
        for (int j = 0; j < 4; j++) {
            float4 lo = *(const float4*)(arow[j] + kk * 32 + quad * 8);
            float4 hi = *(const float4*)(arow[j] + kk * 32 + quad * 8 + 4);
            af[j][0] = (short)f2bf(lo.x); af[j][1] = (short)f2bf(lo.y);
            af[j][2] = (short)f2bf(lo.z); af[j][3] = (short)f2bf(lo.w);
            af[j][4] = (short)f2bf(hi.x); af[j][5] = (short)f2bf(hi.y);
            af[j][6] = (short)f2bf(hi.z); af[j][7] = (short)f2bf(hi.w);
        }
        #pragma unroll
        for (int f = 0; f < 4; f++) {
            int nl = wn * 64 + f * 16 + fr;
            int lb = (nl * 512 + (kk * 32 + quad * 8) * 2) ^ ((nl & 7) << 4);
            bf16x8 bfr = *(const bf16x8*)(smem + lb);
            #pragma unroll
            for (int j = 0; j < 4; j++)
                acc[j][f] = __builtin_amdgcn_mfma_f32_16x16x32_bf16(af[j], bfr, acc[j][f], 0, 0, 0);
        }
    }
    __syncthreads();   // done with B LDS

    // fused el/er from fragments: wave's col range = head wn
    {
        float al4[4], ar4[4];
        #pragma unroll
        for (int f = 0; f < 4; f++) {
            al4[f] = al[wn * 64 + f * 16 + fr];
            ar4[f] = ar[wn * 64 + f * 16 + fr];
        }
        #pragma unroll
        for (int j = 0; j < 4; j++)
            #pragma unroll
            for (int r = 0; r < 4; r++) {
                float pl = 0.f, pr = 0.f;
                #pragma unroll
                for (int f = 0; f < 4; f++) {
                    pl = fmaf(acc[j][f][r], al4[f], pl);
                    pr = fmaf(acc[j][f][r], ar4[f], pr);
                }
                #pragma unroll
                for (int off = 1; off < 16; off <<= 1) {
                    pl += __shfl_xor(pl, off);
                    pr += __shfl_xor(pr, off);
                }
                if (fr == 0) {
                    int gr = m0 + wm * 64 + j * 16 + quad * 4 + r;
                    if (gr < M) {
                        el[gr * NH + wn] = pl;
                        er[gr * NH + wn] = pr;
                    }
                }
            }
    }

    // epilogue: 2 phases of 64 rows, stride-257 f32 bounce, emit packed bf16
    float* eb = (float*)smem;
    #pragma unroll
    for (int p = 0; p < 2; p++) {
        if (wm == p) {
            #pragma unroll
            for (int j = 0; j < 4; j++)
                #pragma unroll
                for (int f = 0; f < 4; f++)
                    #pragma unroll
                    for (int r = 0; r < 4; r++)
                        eb[(j * 16 + quad * 4 + r) * 257 + wn * 64 + f * 16 + fr] = acc[j][f][r];
        }
        __syncthreads();
        {
            int r = tid >> 3;                    // 0..63
            int cbase = (tid & 7) * 32;
            int gr = m0 + p * 64 + r;
            if (gr < M) {
                unsigned short tmp[32];
                #pragma unroll
                for (int i = 0; i < 32; i++) tmp[i] = f2bf(eb[r * 257 + cbase + i]);
                unsigned short* dp = ftb + (size_t)gr * HD + cbase;
                #pragma unroll
                for (int c = 0; c < 4; c++)
                    *(bf16x8*)(dp + c * 8) = *(const bf16x8*)(tmp + c * 8);
            }
        }
        __syncthreads();
    }
}

// ---------------- edge pass: histogram + softmax denominators (atomics) ----------------
__global__ __launch_bounds__(256) void k_edge(const int* __restrict__ src,
                                              const int* __restrict__ dst,
                                              const float* __restrict__ el,
                                              const float* __restrict__ er,
                                              int* __restrict__ counts,
                                              float* __restrict__ denom) {
    int e = blockIdx.x * 256 + threadIdx.x;
    if (e >= N_EDGES) return;
    int s = src[e], d = dst[e];
    atomicAdd(&counts[d], 1);
    float4 l4 = ((const float4*)el)[s];
    float4 r4 = ((const float4*)er)[d];
    float x;
    x = l4.x + r4.x; x = (x > 0.f) ? x : ALPHA * x; float w0 = __expf(x);
    x = l4.y + r4.y; x = (x > 0.f) ? x : ALPHA * x; float w1 = __expf(x);
    x = l4.z + r4.z; x = (x > 0.f) ? x : ALPHA * x; float w2 = __expf(x);
    x = l4.w + r4.w; x = (x > 0.f) ? x : ALPHA * x; float w3 = __expf(x);
    float* dp = denom + (size_t)d * NH;
    atomicAdd(dp + 0, w0);
    atomicAdd(dp + 1, w1);
    atomicAdd(dp + 2, w2);
    atomicAdd(dp + 3, w3);
}

// ---------------- CSR scan ----------------
__global__ __launch_bounds__(512) void k_scan1(const int* __restrict__ counts,
                                               int* __restrict__ incl,
                                               int* __restrict__ bsum, int N) {
    __shared__ int sm[512];
    int i = blockIdx.x * 512 + threadIdx.x;
    int v = (i < N) ? counts[i] : 0;
    sm[threadIdx.x] = v;
    __syncthreads();
    for (int off = 1; off < 512; off <<= 1) {
        int t = (threadIdx.x >= off) ? sm[threadIdx.x - off] : 0;
        __syncthreads();
        sm[threadIdx.x] += t;
        __syncthreads();
    }
    if (i < N) incl[i] = sm[threadIdx.x];
    if (threadIdx.x == 511) bsum[blockIdx.x] = sm[511];
}

__global__ __launch_bounds__(128) void k_scan2(int* __restrict__ bsum, int nb) {
    __shared__ int sm[128];
    int v = (threadIdx.x < nb) ? bsum[threadIdx.x] : 0;
    sm[threadIdx.x] = v;
    __syncthreads();
    for (int off = 1; off < 128; off <<= 1) {
        int t = (threadIdx.x >= off) ? sm[threadIdx.x - off] : 0;
        __syncthreads();
        sm[threadIdx.x] += t;
        __syncthreads();
    }
    if (threadIdx.x < nb) bsum[threadIdx.x] = sm[threadIdx.x] - v;  // exclusive
}

__global__ __launch_bounds__(256) void k_scan3(const int* __restrict__ counts,
                                               const int* __restrict__ incl,
                                               const int* __restrict__ bsum,
                                               int* __restrict__ offs,
                                               int* __restrict__ cursor, int N) {
    int i = blockIdx.x * blockDim.x + threadIdx.x;
    if (i < N) {
        int o = incl[i] - counts[i] + bsum[i >> 9];
        offs[i] = o;
        cursor[i] = o;
    }
}

// ---------------- scatter: CSR adjacency (src ids only) ----------------
__global__ __launch_bounds__(256) void k_scatter(const int* __restrict__ src,
                                                 const int* __restrict__ dst,
                                                 int* __restrict__ cursor,
                                                 int* __restrict__ esrc) {
    int e = blockIdx.x * blockDim.x + threadIdx.x;
    if (e < N_EDGES) {
        int p = atomicAdd(&cursor[dst[e]], 1);
        esrc[p] = src[e];
    }
}

// ---------------- Aggregation: one wave per destination node ----------------
__global__ __launch_bounds__(256) void k_agg(const unsigned short* __restrict__ ftb,
                                             const float* __restrict__ el,
                                             const float* __restrict__ er,
                                             const float* __restrict__ denom,
                                             const int* __restrict__ offs,
                                             const int* __restrict__ counts,
                                             const int* __restrict__ esrc,
                                             float* __restrict__ out, int N) {
    int wid = (blockIdx.x * 256 + threadIdx.x) >> 6;
    int lane = threadIdx.x & 63;
    if (wid >= N) return;
    const int deg = counts[wid];
    const int start = offs[wid];
    const int quad = lane >> 4;

    float dq = denom[wid * NH + quad];
    float invd = (deg > 0 && dq > 0.f) ? 1.f / dq : 0.f;
    float erq = er[wid * NH + quad];

    float a0 = 0.f, a1 = 0.f, a2 = 0.f, a3 = 0.f;
    #pragma unroll 4
    for (int i = 0; i < deg; i++) {
        int sv = esrc[start + i];
        float x = el[sv * NH + quad] + erq;       // 4-B broadcast gather (L2-hot)
        x = (x > 0.f) ? x : ALPHA * x;
        float we = __expf(x);
        ushort4 fv = ((const ushort4*)ftb)[(size_t)sv * 64 + lane];
        a0 = fmaf(we, bf2f(fv.x), a0);
        a1 = fmaf(we, bf2f(fv.y), a1);
        a2 = fmaf(we, bf2f(fv.z), a2);
        a3 = fmaf(we, bf2f(fv.w), a3);
    }
    float4 o = make_float4(a0 * invd, a1 * invd, a2 * invd, a3 * invd);
    ((float4*)out)[(size_t)wid * 64 + lane] = o;
}

// ---------------- launch ----------------
extern "C" void kernel_launch(void* const* d_in, const int* in_sizes, int n_in,
                              void* d_out, int out_size, void* d_ws, size_t ws_size,
                              hipStream_t stream) {
    const float* feat = (const float*)d_in[0];
    const float* fc_w = (const float*)d_in[1];
    const float* attn_l = (const float*)d_in[2];
    const float* attn_r = (const float*)d_in[3];
    const int* src = (const int*)d_in[4];
    const int* dst = (const int*)d_in[5];
    float* out = (float*)d_out;

    char* w = (char*)d_ws;
    unsigned short* ftb = (unsigned short*)w;  w += (size_t)N_NODES * HD * 2;      // 25.6 MB
    unsigned short* Bt = (unsigned short*)w;   w += (size_t)IN_F * HD * 2;         // 128 KB
    float* el = (float*)w;       w += (size_t)N_NODES * NH * 4;                    // 800 KB
    float* er = (float*)w;       w += (size_t)N_NODES * NH * 4;                    // 800 KB
    int* counts = (int*)w;       w += (size_t)N_NODES * 4;                         // 200 KB
    float* denom = (float*)w;    w += (size_t)N_NODES * NH * 4;                    // 800 KB (contiguous w/ counts)
    int* incl = (int*)w;         w += (size_t)N_NODES * 4;
    int* offs = (int*)w;         w += (size_t)N_NODES * 4;
    int* cursor = (int*)w;       w += (size_t)N_NODES * 4;
    int* bsum = (int*)w;         w += 1024;
    int* esrc = (int*)w;         w += (size_t)N_EDGES * 4;                          // 3.2 MB

    // zero counts + denom in one shot (contiguous)
    hipMemsetAsync(counts, 0, (size_t)N_NODES * 4 + (size_t)N_NODES * NH * 4, stream);

    k_cvt_w<<<256, 256, 0, stream>>>(fc_w, Bt);

    k_gemm<<<(N_NODES + 127) / 128, 512, 0, stream>>>(feat, Bt, ftb, el, er,
                                                      attn_l, attn_r, N_NODES);

    int eblocks = (N_EDGES + 255) / 256;
    k_edge<<<eblocks, 256, 0, stream>>>(src, dst, el, er, counts, denom);

    int nsb = (N_NODES + 511) / 512;
    k_scan1<<<nsb, 512, 0, stream>>>(counts, incl, bsum, N_NODES);
    k_scan2<<<1, 128, 0, stream>>>(bsum, nsb);
    k_scan3<<<(N_NODES + 255) / 256, 256, 0, stream>>>(counts, incl, bsum, offs, cursor, N_NODES);
    k_scatter<<<eblocks, 256, 0, stream>>>(src, dst, cursor, esrc);

    int agg_blocks = (N_NODES * 64 + 255) / 256;
    k_agg<<<agg_blocks, 256, 0, stream>>>(ftb, el, er, denom, offs, counts, esrc, out, N_NODES);
}

// Round 4
// 224.148 us; speedup vs baseline: 1.7001x; 1.7001x over previous
//
#include <hip/hip_runtime.h>
#include <hip/hip_bf16.h>

#define N_NODES 50000
#define N_EDGES 800000
#define IN_F 256
#define NH 4
#define DH 64
#define HD 256
#define ALPHA 0.2f

typedef short bf16x8 __attribute__((ext_vector_type(8)));
typedef float f32x4 __attribute__((ext_vector_type(4)));

__device__ __forceinline__ unsigned short f2bf(float f) {
    unsigned u = __float_as_uint(f);
    u = (u + 0x7FFFu + ((u >> 16) & 1u)) >> 16;   // RNE
    return (unsigned short)u;
}
__device__ __forceinline__ float bf2f(unsigned short h) {
    return __uint_as_float(((unsigned)h) << 16);
}

// ---------------- fc_w [k][n] fp32 -> Bt [n][k] bf16 (transpose + convert) ----------
__global__ __launch_bounds__(256) void k_cvt_w(const float* __restrict__ fw,
                                               unsigned short* __restrict__ Bt) {
    int n = blockIdx.x;            // 0..255
    int k = threadIdx.x;           // 0..255
    Bt[n * 256 + k] = f2bf(fw[k * 256 + n]);
}

// ---------------- GEMM: ftb = bf16( feat @ fc_w ) + fused el/er ----------------
// BM=128, BN=256 (full), 512 threads = 8 waves as 2M x 4N; each wave's 64-col slice = one head
__global__ __launch_bounds__(512) void k_gemm(const float* __restrict__ A,
                                              const unsigned short* __restrict__ Bt,
                                              unsigned short* __restrict__ ftb,
                                              float* __restrict__ el,
                                              float* __restrict__ er,
                                              const float* __restrict__ al,
                                              const float* __restrict__ ar, int M) {
    __shared__ __align__(16) char smem[131072];   // B-tile 256x256 bf16 (swizzled); reused as 64x257 f32 x2 phases
    const int tid = threadIdx.x;
    const int m0 = blockIdx.x * 128;

    // stage full B [256][256] bf16, lane-contiguous global reads, XOR-swizzled LDS
    #pragma unroll
    for (int c = 0; c < 16; c++) {
        int o = c * 8192 + tid * 16;            // byte offset, 131072 total
        bf16x8 v = *(const bf16x8*)((const char*)Bt + o);
        int nl = o >> 9;
        int lb = o ^ ((nl & 7) << 4);
        *(bf16x8*)(smem + lb) = v;
    }
    __syncthreads();

    const int w = tid >> 6, lane = tid & 63;
    const int wm = w >> 2, wn = w & 3;          // 2 x 4
    const int fr = lane & 15, quad = lane >> 4;

    const float* arow[4];
    int grow[4];
    #pragma unroll
    for (int j = 0; j < 4; j++) {
        grow[j] = m0 + wm * 64 + j * 16 + fr;
        int cr = grow[j] < M ? grow[j] : (M - 1);
        arow[j] = A + (size_t)cr * IN_F;
    }

    f32x4 acc[4][4];
    #pragma unroll
    for (int j = 0; j < 4; j++)
        #pragma unroll
        for (int f = 0; f < 4; f++) acc[j][f] = (f32x4){0.f, 0.f, 0.f, 0.f};

    #pragma unroll
    for (int kk = 0; kk < 8; kk++) {
        bf16x8 af[4];
        #pragma unroll
        for (int j = 0; j < 4; j++) {
            float4 lo = *(const float4*)(arow[j] + kk * 32 + quad * 8);
            float4 hi = *(const float4*)(arow[j] + kk * 32 + quad * 8 + 4);
            af[j][0] = (short)f2bf(lo.x); af[j][1] = (short)f2bf(lo.y);
            af[j][2] = (short)f2bf(lo.z); af[j][3] = (short)f2bf(lo.w);
            af[j][4] = (short)f2bf(hi.x); af[j][5] = (short)f2bf(hi.y);
            af[j][6] = (short)f2bf(hi.z); af[j][7] = (short)f2bf(hi.w);
        }
        #pragma unroll
        for (int f = 0; f < 4; f++) {
            int nl = wn * 64 + f * 16 + fr;
            int lb = (nl * 512 + (kk * 32 + quad * 8) * 2) ^ ((nl & 7) << 4);
            bf16x8 bfr = *(const bf16x8*)(smem + lb);
            #pragma unroll
            for (int j = 0; j < 4; j++)
                acc[j][f] = __builtin_amdgcn_mfma_f32_16x16x32_bf16(af[j], bfr, acc[j][f], 0, 0, 0);
        }
    }
    __syncthreads();   // done with B LDS

    // fused el/er from fragments: wave's col range = head wn
    {
        float al4[4], ar4[4];
        #pragma unroll
        for (int f = 0; f < 4; f++) {
            al4[f] = al[wn * 64 + f * 16 + fr];
            ar4[f] = ar[wn * 64 + f * 16 + fr];
        }
        #pragma unroll
        for (int j = 0; j < 4; j++)
            #pragma unroll
            for (int r = 0; r < 4; r++) {
                float pl = 0.f, pr = 0.f;
                #pragma unroll
                for (int f = 0; f < 4; f++) {
                    pl = fmaf(acc[j][f][r], al4[f], pl);
                    pr = fmaf(acc[j][f][r], ar4[f], pr);
                }
                #pragma unroll
                for (int off = 1; off < 16; off <<= 1) {
                    pl += __shfl_xor(pl, off);
                    pr += __shfl_xor(pr, off);
                }
                if (fr == 0) {
                    int gr = m0 + wm * 64 + j * 16 + quad * 4 + r;
                    if (gr < M) {
                        el[gr * NH + wn] = pl;
                        er[gr * NH + wn] = pr;
                    }
                }
            }
    }

    // epilogue: 2 phases of 64 rows, stride-257 f32 bounce, emit packed bf16
    float* eb = (float*)smem;
    #pragma unroll
    for (int p = 0; p < 2; p++) {
        if (wm == p) {
            #pragma unroll
            for (int j = 0; j < 4; j++)
                #pragma unroll
                for (int f = 0; f < 4; f++)
                    #pragma unroll
                    for (int r = 0; r < 4; r++)
                        eb[(j * 16 + quad * 4 + r) * 257 + wn * 64 + f * 16 + fr] = acc[j][f][r];
        }
        __syncthreads();
        {
            int r = tid >> 3;                    // 0..63
            int cbase = (tid & 7) * 32;
            int gr = m0 + p * 64 + r;
            if (gr < M) {
                unsigned short tmp[32];
                #pragma unroll
                for (int i = 0; i < 32; i++) tmp[i] = f2bf(eb[r * 257 + cbase + i]);
                unsigned short* dp = ftb + (size_t)gr * HD + cbase;
                #pragma unroll
                for (int c = 0; c < 4; c++)
                    *(bf16x8*)(dp + c * 8) = *(const bf16x8*)(tmp + c * 8);
            }
        }
        __syncthreads();
    }
}

// ---------------- histogram: counts only (int atomics) ----------------
__global__ __launch_bounds__(256) void k_hist(const int* __restrict__ dst, int* __restrict__ counts) {
    int e = blockIdx.x * blockDim.x + threadIdx.x;
    if (e < N_EDGES) atomicAdd(&counts[dst[e]], 1);
}

// ---------------- CSR scan ----------------
__global__ __launch_bounds__(512) void k_scan1(const int* __restrict__ counts,
                                               int* __restrict__ incl,
                                               int* __restrict__ bsum, int N) {
    __shared__ int sm[512];
    int i = blockIdx.x * 512 + threadIdx.x;
    int v = (i < N) ? counts[i] : 0;
    sm[threadIdx.x] = v;
    __syncthreads();
    for (int off = 1; off < 512; off <<= 1) {
        int t = (threadIdx.x >= off) ? sm[threadIdx.x - off] : 0;
        __syncthreads();
        sm[threadIdx.x] += t;
        __syncthreads();
    }
    if (i < N) incl[i] = sm[threadIdx.x];
    if (threadIdx.x == 511) bsum[blockIdx.x] = sm[511];
}

__global__ __launch_bounds__(128) void k_scan2(int* __restrict__ bsum, int nb) {
    __shared__ int sm[128];
    int v = (threadIdx.x < nb) ? bsum[threadIdx.x] : 0;
    sm[threadIdx.x] = v;
    __syncthreads();
    for (int off = 1; off < 128; off <<= 1) {
        int t = (threadIdx.x >= off) ? sm[threadIdx.x - off] : 0;
        __syncthreads();
        sm[threadIdx.x] += t;
        __syncthreads();
    }
    if (threadIdx.x < nb) bsum[threadIdx.x] = sm[threadIdx.x] - v;  // exclusive
}

__global__ __launch_bounds__(256) void k_scan3(const int* __restrict__ counts,
                                               const int* __restrict__ incl,
                                               const int* __restrict__ bsum,
                                               int* __restrict__ offs,
                                               int* __restrict__ cursor, int N) {
    int i = blockIdx.x * blockDim.x + threadIdx.x;
    if (i < N) {
        int o = incl[i] - counts[i] + bsum[i >> 9];
        offs[i] = o;
        cursor[i] = o;
    }
}

// ---------------- scatter: CSR adjacency (src ids only) ----------------
__global__ __launch_bounds__(256) void k_scatter(const int* __restrict__ src,
                                                 const int* __restrict__ dst,
                                                 int* __restrict__ cursor,
                                                 int* __restrict__ esrc) {
    int e = blockIdx.x * blockDim.x + threadIdx.x;
    if (e < N_EDGES) {
        int p = atomicAdd(&cursor[dst[e]], 1);
        esrc[p] = src[e];
    }
}

// ---------------- Aggregation: one wave per destination node ----------------
__global__ __launch_bounds__(256) void k_agg(const unsigned short* __restrict__ ftb,
                                             const float* __restrict__ el,
                                             const float* __restrict__ er,
                                             const int* __restrict__ offs,
                                             const int* __restrict__ counts,
                                             const int* __restrict__ esrc,
                                             float* __restrict__ out, int N) {
    int wid = (blockIdx.x * 256 + threadIdx.x) >> 6;
    int lane = threadIdx.x & 63;
    if (wid >= N) return;
    const int deg = counts[wid];
    const int start = offs[wid];
    const int quad = lane >> 4;

    float4 r4 = ((const float4*)er)[wid];   // node-uniform

    // pass 1: softmax denominators — lane-parallel over edges, el 16-B gather (L2-hot)
    float sx = 0.f, sy = 0.f, sz = 0.f, sw = 0.f;
    for (int i = lane; i < deg; i += 64) {
        int sv = esrc[start + i];
        float4 l4 = ((const float4*)el)[sv];
        float x;
        x = l4.x + r4.x; x = (x > 0.f) ? x : ALPHA * x; sx += __expf(x);
        x = l4.y + r4.y; x = (x > 0.f) ? x : ALPHA * x; sy += __expf(x);
        x = l4.z + r4.z; x = (x > 0.f) ? x : ALPHA * x; sz += __expf(x);
        x = l4.w + r4.w; x = (x > 0.f) ? x : ALPHA * x; sw += __expf(x);
    }
    #pragma unroll
    for (int off = 1; off < 64; off <<= 1) {
        sx += __shfl_xor(sx, off);
        sy += __shfl_xor(sy, off);
        sz += __shfl_xor(sz, off);
        sw += __shfl_xor(sw, off);
    }
    float dq = (quad == 0) ? sx : (quad == 1) ? sy : (quad == 2) ? sz : sw;
    float invd = (deg > 0 && dq > 0.f) ? 1.f / dq : 0.f;
    float erq = (quad == 0) ? r4.x : (quad == 1) ? r4.y : (quad == 2) ? r4.z : r4.w;

    // pass 2: weighted gather-accumulate; lane owns 4 consecutive cols (one head)
    float a0 = 0.f, a1 = 0.f, a2 = 0.f, a3 = 0.f;
    #pragma unroll 4
    for (int i = 0; i < deg; i++) {
        int sv = esrc[start + i];                 // wave-uniform (L1-hot from pass 1)
        float x = el[sv * NH + quad] + erq;       // 4-B broadcast gather (L1/L2-hot)
        x = (x > 0.f) ? x : ALPHA * x;
        float we = __expf(x);
        ushort4 fv = ((const ushort4*)ftb)[(size_t)sv * 64 + lane];
        a0 = fmaf(we, bf2f(fv.x), a0);
        a1 = fmaf(we, bf2f(fv.y), a1);
        a2 = fmaf(we, bf2f(fv.z), a2);
        a3 = fmaf(we, bf2f(fv.w), a3);
    }
    float4 o = make_float4(a0 * invd, a1 * invd, a2 * invd, a3 * invd);
    ((float4*)out)[(size_t)wid * 64 + lane] = o;
}

// ---------------- launch ----------------
extern "C" void kernel_launch(void* const* d_in, const int* in_sizes, int n_in,
                              void* d_out, int out_size, void* d_ws, size_t ws_size,
                              hipStream_t stream) {
    const float* feat = (const float*)d_in[0];
    const float* fc_w = (const float*)d_in[1];
    const float* attn_l = (const float*)d_in[2];
    const float* attn_r = (const float*)d_in[3];
    const int* src = (const int*)d_in[4];
    const int* dst = (const int*)d_in[5];
    float* out = (float*)d_out;

    char* w = (char*)d_ws;
    unsigned short* ftb = (unsigned short*)w;  w += (size_t)N_NODES * HD * 2;      // 25.6 MB
    unsigned short* Bt = (unsigned short*)w;   w += (size_t)IN_F * HD * 2;         // 128 KB
    float* el = (float*)w;       w += (size_t)N_NODES * NH * 4;                    // 800 KB
    float* er = (float*)w;       w += (size_t)N_NODES * NH * 4;                    // 800 KB
    int* counts = (int*)w;       w += (size_t)N_NODES * 4;                         // 200 KB
    int* incl = (int*)w;         w += (size_t)N_NODES * 4;
    int* offs = (int*)w;         w += (size_t)N_NODES * 4;
    int* cursor = (int*)w;       w += (size_t)N_NODES * 4;
    int* bsum = (int*)w;         w += 1024;
    int* esrc = (int*)w;         w += (size_t)N_EDGES * 4;                          // 3.2 MB

    hipMemsetAsync(counts, 0, (size_t)N_NODES * 4, stream);

    k_cvt_w<<<256, 256, 0, stream>>>(fc_w, Bt);

    k_gemm<<<(N_NODES + 127) / 128, 512, 0, stream>>>(feat, Bt, ftb, el, er,
                                                      attn_l, attn_r, N_NODES);

    int eblocks = (N_EDGES + 255) / 256;
    k_hist<<<eblocks, 256, 0, stream>>>(dst, counts);

    int nsb = (N_NODES + 511) / 512;
    k_scan1<<<nsb, 512, 0, stream>>>(counts, incl, bsum, N_NODES);
    k_scan2<<<1, 128, 0, stream>>>(bsum, nsb);
    k_scan3<<<(N_NODES + 255) / 256, 256, 0, stream>>>(counts, incl, bsum, offs, cursor, N_NODES);
    k_scatter<<<eblocks, 256, 0, stream>>>(src, dst, cursor, esrc);

    int agg_blocks = (N_NODES * 64 + 255) / 256;
    k_agg<<<agg_blocks, 256, 0, stream>>>(ftb, el, er, offs, counts, esrc, out, N_NODES);
}

// Round 5
// 217.342 us; speedup vs baseline: 1.7533x; 1.0313x over previous
//
#include <hip/hip_runtime.h>
#include <hip/hip_bf16.h>

#define N_NODES 50000
#define N_EDGES 800000
#define IN_F 256
#define NH 4
#define DH 64
#define HD 256
#define ALPHA 0.2f

typedef short bf16x8 __attribute__((ext_vector_type(8)));
typedef float f32x4 __attribute__((ext_vector_type(4)));

__device__ __forceinline__ unsigned short f2bf(float f) {
    unsigned u = __float_as_uint(f);
    u = (u + 0x7FFFu + ((u >> 16) & 1u)) >> 16;   // RNE
    return (unsigned short)u;
}
__device__ __forceinline__ float bf2f(unsigned short h) {
    return __uint_as_float(((unsigned)h) << 16);
}

// ---------------- fused prep: Bt transpose-convert + dst histogram ----------------
__global__ __launch_bounds__(256) void k_prep(const float* __restrict__ fw,
                                              unsigned short* __restrict__ Bt,
                                              const int* __restrict__ dst,
                                              int* __restrict__ counts) {
    if (blockIdx.x < 256) {
        int n = blockIdx.x;            // 0..255
        int k = threadIdx.x;           // 0..255
        Bt[n * 256 + k] = f2bf(fw[k * 256 + n]);
    } else {
        int e = (blockIdx.x - 256) * 256 + threadIdx.x;
        if (e < N_EDGES) atomicAdd(&counts[dst[e]], 1);
    }
}

// ---------------- GEMM: ftb = bf16( feat @ fc_w ) + fused el/er ----------------
// BM=64, BN=256 (full width), 256 threads = 4 waves, wave wn owns head wn.
// No LDS: B fragments straight from L2; swapped-operand MFMA so lane&15 = output ROW
// -> direct packed bf16 row-major stores, el/er reduce = shfl_xor(16,32).
__global__ __launch_bounds__(256) void k_gemm(const float* __restrict__ A,
                                              const unsigned short* __restrict__ Bt,
                                              unsigned short* __restrict__ ftb,
                                              float* __restrict__ el,
                                              float* __restrict__ er,
                                              const float* __restrict__ al,
                                              const float* __restrict__ ar, int M) {
    const int tid = threadIdx.x;
    const int m0 = blockIdx.x * 64;
    const int wn = tid >> 6;                    // head / 64-col slice
    const int lane = tid & 63;
    const int fr = lane & 15, quad = lane >> 4;

    const float* arow[4];
    int gm[4];
    #pragma unroll
    for (int j = 0; j < 4; j++) {
        gm[j] = m0 + j * 16 + fr;
        int cr = gm[j] < M ? gm[j] : (M - 1);
        arow[j] = A + (size_t)cr * IN_F;
    }
    const unsigned short* bp = Bt + (size_t)(wn * 64) * 256;

    f32x4 acc[4][4];
    #pragma unroll
    for (int j = 0; j < 4; j++)
        #pragma unroll
        for (int f = 0; f < 4; f++) acc[j][f] = (f32x4){0.f, 0.f, 0.f, 0.f};

    #pragma unroll
    for (int kk = 0; kk < 8; kk++) {
        bf16x8 af[4];
        #pragma unroll
        for (int j = 0; j < 4; j++) {
            float4 lo = *(const float4*)(arow[j] + kk * 32 + quad * 8);
            float4 hi = *(const float4*)(arow[j] + kk * 32 + quad * 8 + 4);
            af[j][0] = (short)f2bf(lo.x); af[j][1] = (short)f2bf(lo.y);
            af[j][2] = (short)f2bf(lo.z); af[j][3] = (short)f2bf(lo.w);
            af[j][4] = (short)f2bf(hi.x); af[j][5] = (short)f2bf(hi.y);
            af[j][6] = (short)f2bf(hi.z); af[j][7] = (short)f2bf(hi.w);
        }
        #pragma unroll
        for (int f = 0; f < 4; f++) {
            bf16x8 bfr = *(const bf16x8*)(bp + (size_t)(f * 16 + fr) * 256 + kk * 32 + quad * 8);
            #pragma unroll
            for (int j = 0; j < 4; j++)
                acc[j][f] = __builtin_amdgcn_mfma_f32_16x16x32_bf16(bfr, af[j], acc[j][f], 0, 0, 0);
        }
    }
    // layout now: for (j,f): lane holds D[row = m0+j*16+fr][col = wn*64+f*16+quad*4+r]

    // fused el/er (head wn): per-lane partial over its 16 cols, reduce across quads
    #pragma unroll
    for (int j = 0; j < 4; j++) {
        float pl = 0.f, pr = 0.f;
        #pragma unroll
        for (int f = 0; f < 4; f++) {
            float4 a4 = *(const float4*)(al + wn * 64 + f * 16 + quad * 4);
            float4 b4 = *(const float4*)(ar + wn * 64 + f * 16 + quad * 4);
            pl += acc[j][f][0] * a4.x + acc[j][f][1] * a4.y + acc[j][f][2] * a4.z + acc[j][f][3] * a4.w;
            pr += acc[j][f][0] * b4.x + acc[j][f][1] * b4.y + acc[j][f][2] * b4.z + acc[j][f][3] * b4.w;
        }
        pl += __shfl_xor(pl, 16); pl += __shfl_xor(pl, 32);
        pr += __shfl_xor(pr, 16); pr += __shfl_xor(pr, 32);
        if (quad == 0 && gm[j] < M) {
            el[gm[j] * NH + wn] = pl;
            er[gm[j] * NH + wn] = pr;
        }
    }

    // direct bf16 stores: 8 B per (j,f), row-major
    #pragma unroll
    for (int j = 0; j < 4; j++) {
        if (gm[j] < M) {
            unsigned short* dp = ftb + (size_t)gm[j] * HD + wn * 64 + quad * 4;
            #pragma unroll
            for (int f = 0; f < 4; f++) {
                ushort4 pk;
                pk.x = f2bf(acc[j][f][0]);
                pk.y = f2bf(acc[j][f][1]);
                pk.z = f2bf(acc[j][f][2]);
                pk.w = f2bf(acc[j][f][3]);
                *(ushort4*)(dp + f * 16) = pk;
            }
        }
    }
}

// ---------------- CSR scan ----------------
__global__ __launch_bounds__(512) void k_scan1(const int* __restrict__ counts,
                                               int* __restrict__ incl,
                                               int* __restrict__ bsum, int N) {
    __shared__ int sm[512];
    int i = blockIdx.x * 512 + threadIdx.x;
    int v = (i < N) ? counts[i] : 0;
    sm[threadIdx.x] = v;
    __syncthreads();
    for (int off = 1; off < 512; off <<= 1) {
        int t = (threadIdx.x >= off) ? sm[threadIdx.x - off] : 0;
        __syncthreads();
        sm[threadIdx.x] += t;
        __syncthreads();
    }
    if (i < N) incl[i] = sm[threadIdx.x];
    if (threadIdx.x == 511) bsum[blockIdx.x] = sm[511];
}

__global__ __launch_bounds__(128) void k_scan2(int* __restrict__ bsum, int nb) {
    __shared__ int sm[128];
    int v = (threadIdx.x < nb) ? bsum[threadIdx.x] : 0;
    sm[threadIdx.x] = v;
    __syncthreads();
    for (int off = 1; off < 128; off <<= 1) {
        int t = (threadIdx.x >= off) ? sm[threadIdx.x - off] : 0;
        __syncthreads();
        sm[threadIdx.x] += t;
        __syncthreads();
    }
    if (threadIdx.x < nb) bsum[threadIdx.x] = sm[threadIdx.x] - v;  // exclusive
}

__global__ __launch_bounds__(256) void k_scan3(const int* __restrict__ counts,
                                               const int* __restrict__ incl,
                                               const int* __restrict__ bsum,
                                               int* __restrict__ offs,
                                               int* __restrict__ cursor, int N) {
    int i = blockIdx.x * blockDim.x + threadIdx.x;
    if (i < N) {
        int o = incl[i] - counts[i] + bsum[i >> 9];
        offs[i] = o;
        cursor[i] = o;
    }
}

// ---------------- scatter: CSR adjacency (src ids only) ----------------
__global__ __launch_bounds__(256) void k_scatter(const int* __restrict__ src,
                                                 const int* __restrict__ dst,
                                                 int* __restrict__ cursor,
                                                 int* __restrict__ esrc) {
    int e = blockIdx.x * blockDim.x + threadIdx.x;
    if (e < N_EDGES) {
        int p = atomicAdd(&cursor[dst[e]], 1);
        esrc[p] = src[e];
    }
}

// ---------------- Aggregation: one wave per destination node ----------------
// LDS weight cache: pass 1 computes exp-weights once (lane-parallel) into a
// wave-private 4 KB slab; pass 2 is pure {ds_read broadcast + ftb gather + FMA}.
__global__ __launch_bounds__(256) void k_agg(const unsigned short* __restrict__ ftb,
                                             const float* __restrict__ el,
                                             const float* __restrict__ er,
                                             const int* __restrict__ offs,
                                             const int* __restrict__ counts,
                                             const int* __restrict__ esrc,
                                             float* __restrict__ out, int N) {
    __shared__ float4 wcache[4][256];           // 16 KB: 4 waves x 256 edges
    const int wv = threadIdx.x >> 6;
    int wid = (blockIdx.x * 256 + threadIdx.x) >> 6;
    const int lane = threadIdx.x & 63;
    if (wid >= N) return;
    const int deg = counts[wid];
    const int start = offs[wid];
    const int quad = lane >> 4;
    float4* wc = &wcache[wv][0];
    const float* wf = (const float*)wc;

    float4 r4 = ((const float4*)er)[wid];       // node-uniform

    float sx = 0.f, sy = 0.f, sz = 0.f, sw = 0.f;
    float a0 = 0.f, a1 = 0.f, a2 = 0.f, a3 = 0.f;

    for (int c0 = 0; c0 < deg; c0 += 256) {
        int clen = min(deg - c0, 256);
        // pass 1: weights into LDS + denominator partials
        for (int i = lane; i < clen; i += 64) {
            int sv = esrc[start + c0 + i];
            float4 l4 = ((const float4*)el)[sv];
            float x;
            x = l4.x + r4.x; x = (x > 0.f) ? x : ALPHA * x; float w0 = __expf(x);
            x = l4.y + r4.y; x = (x > 0.f) ? x : ALPHA * x; float w1 = __expf(x);
            x = l4.z + r4.z; x = (x > 0.f) ? x : ALPHA * x; float w2 = __expf(x);
            x = l4.w + r4.w; x = (x > 0.f) ? x : ALPHA * x; float w3 = __expf(x);
            wc[i] = make_float4(w0, w1, w2, w3);
            sx += w0; sy += w1; sz += w2; sw += w3;
        }
        // pass 2: weighted gather-accumulate (wave-private LDS, no barrier needed)
        #pragma unroll 4
        for (int i = 0; i < clen; i++) {
            int sv = esrc[start + c0 + i];            // L1-hot reload
            float we = wf[i * 4 + quad];              // broadcast ds_read
            ushort4 fv = ((const ushort4*)ftb)[(size_t)sv * 64 + lane];
            a0 = fmaf(we, bf2f(fv.x), a0);
            a1 = fmaf(we, bf2f(fv.y), a1);
            a2 = fmaf(we, bf2f(fv.z), a2);
            a3 = fmaf(we, bf2f(fv.w), a3);
        }
    }
    #pragma unroll
    for (int off = 1; off < 64; off <<= 1) {
        sx += __shfl_xor(sx, off);
        sy += __shfl_xor(sy, off);
        sz += __shfl_xor(sz, off);
        sw += __shfl_xor(sw, off);
    }
    float dq = (quad == 0) ? sx : (quad == 1) ? sy : (quad == 2) ? sz : sw;
    float invd = (deg > 0 && dq > 0.f) ? 1.f / dq : 0.f;

    float4 o = make_float4(a0 * invd, a1 * invd, a2 * invd, a3 * invd);
    ((float4*)out)[(size_t)wid * 64 + lane] = o;
}

// ---------------- launch ----------------
extern "C" void kernel_launch(void* const* d_in, const int* in_sizes, int n_in,
                              void* d_out, int out_size, void* d_ws, size_t ws_size,
                              hipStream_t stream) {
    const float* feat = (const float*)d_in[0];
    const float* fc_w = (const float*)d_in[1];
    const float* attn_l = (const float*)d_in[2];
    const float* attn_r = (const float*)d_in[3];
    const int* src = (const int*)d_in[4];
    const int* dst = (const int*)d_in[5];
    float* out = (float*)d_out;

    char* w = (char*)d_ws;
    unsigned short* ftb = (unsigned short*)w;  w += (size_t)N_NODES * HD * 2;      // 25.6 MB
    unsigned short* Bt = (unsigned short*)w;   w += (size_t)IN_F * HD * 2;         // 128 KB
    float* el = (float*)w;       w += (size_t)N_NODES * NH * 4;                    // 800 KB
    float* er = (float*)w;       w += (size_t)N_NODES * NH * 4;                    // 800 KB
    int* counts = (int*)w;       w += (size_t)N_NODES * 4;
    int* incl = (int*)w;         w += (size_t)N_NODES * 4;
    int* offs = (int*)w;         w += (size_t)N_NODES * 4;
    int* cursor = (int*)w;       w += (size_t)N_NODES * 4;
    int* bsum = (int*)w;         w += 1024;
    int* esrc = (int*)w;         w += (size_t)N_EDGES * 4;                          // 3.2 MB

    hipMemsetAsync(counts, 0, (size_t)N_NODES * 4, stream);

    int eblocks = (N_EDGES + 255) / 256;
    k_prep<<<256 + eblocks, 256, 0, stream>>>(fc_w, Bt, dst, counts);

    k_gemm<<<(N_NODES + 63) / 64, 256, 0, stream>>>(feat, Bt, ftb, el, er,
                                                    attn_l, attn_r, N_NODES);

    int nsb = (N_NODES + 511) / 512;
    k_scan1<<<nsb, 512, 0, stream>>>(counts, incl, bsum, N_NODES);
    k_scan2<<<1, 128, 0, stream>>>(bsum, nsb);
    k_scan3<<<(N_NODES + 255) / 256, 256, 0, stream>>>(counts, incl, bsum, offs, cursor, N_NODES);
    k_scatter<<<eblocks, 256, 0, stream>>>(src, dst, cursor, esrc);

    int agg_blocks = (N_NODES * 64 + 255) / 256;
    k_agg<<<agg_blocks, 256, 0, stream>>>(ftb, el, er, offs, counts, esrc, out, N_NODES);
}

// Round 8
// 206.261 us; speedup vs baseline: 1.8475x; 1.0537x over previous
//
#include <hip/hip_runtime.h>
#include <hip/hip_bf16.h>

#define N_NODES 50000
#define N_EDGES 800000
#define IN_F 256
#define NH 4
#define DH 64
#define HD 256
#define ALPHA 0.2f

typedef short bf16x8 __attribute__((ext_vector_type(8)));
typedef float f32x4 __attribute__((ext_vector_type(4)));

__device__ __forceinline__ unsigned short f2bf(float f) {
    unsigned u = __float_as_uint(f);
    u = (u + 0x7FFFu + ((u >> 16) & 1u)) >> 16;   // RNE
    return (unsigned short)u;
}
__device__ __forceinline__ float bf2f(unsigned short h) {
    return __uint_as_float(((unsigned)h) << 16);
}

// ---------------- fused prep: Bt transpose-convert + dst histogram (8 copies) -------
__global__ __launch_bounds__(256) void k_prep(const float* __restrict__ fw,
                                              unsigned short* __restrict__ Bt,
                                              const int* __restrict__ dst,
                                              int* __restrict__ counts8) {
    if (blockIdx.x < 256) {
        int n = blockIdx.x;            // 0..255
        int k = threadIdx.x;           // 0..255
        Bt[n * 256 + k] = f2bf(fw[k * 256 + n]);
    } else {
        int b = blockIdx.x - 256;
        int e = b * 256 + threadIdx.x;
        if (e < N_EDGES) atomicAdd(&counts8[(b & 7) * N_NODES + dst[e]], 1);
    }
}

// ---------------- GEMM: ftb = bf16( feat @ fc_w ) + fused el/er ----------------
// BM=128, BN=256 (full), 512 threads = 8 waves (2M x 4N); B staged once in LDS
// (XOR-swizzled). Swapped-operand MFMA -> lane&15 = output ROW -> direct packed
// bf16 stores + in-register el/er. One barrier total.
__global__ __launch_bounds__(512) void k_gemm(const float* __restrict__ A,
                                              const unsigned short* __restrict__ Bt,
                                              unsigned short* __restrict__ ftb,
                                              float* __restrict__ el,
                                              float* __restrict__ er,
                                              const float* __restrict__ al,
                                              const float* __restrict__ ar, int M) {
    __shared__ __align__(16) char smem[131072];   // B-tile 256x256 bf16, swizzled
    const int tid = threadIdx.x;
    const int m0 = blockIdx.x * 128;

    #pragma unroll
    for (int c = 0; c < 16; c++) {
        int o = c * 8192 + tid * 16;            // byte offset
        bf16x8 v = *(const bf16x8*)((const char*)Bt + o);
        int nl = o >> 9;
        int lb = o ^ ((nl & 7) << 4);
        *(bf16x8*)(smem + lb) = v;
    }
    __syncthreads();

    const int w = tid >> 6, lane = tid & 63;
    const int wm = w >> 2, wn = w & 3;          // 2 x 4; wave's 64-col slice = head wn
    const int fr = lane & 15, quad = lane >> 4;

    const float* arow[4];
    int gm[4];
    #pragma unroll
    for (int j = 0; j < 4; j++) {
        gm[j] = m0 + wm * 64 + j * 16 + fr;
        int cr = gm[j] < M ? gm[j] : (M - 1);
        arow[j] = A + (size_t)cr * IN_F;
    }

    f32x4 acc[4][4];
    #pragma unroll
    for (int j = 0; j < 4; j++)
        #pragma unroll
        for (int f = 0; f < 4; f++) acc[j][f] = (f32x4){0.f, 0.f, 0.f, 0.f};

    #pragma unroll
    for (int kk = 0; kk < 8; kk++) {
        bf16x8 af[4];
        #pragma unroll
        for (int j = 0; j < 4; j++) {
            float4 lo = *(const float4*)(arow[j] + kk * 32 + quad * 8);
            float4 hi = *(const float4*)(arow[j] + kk * 32 + quad * 8 + 4);
            af[j][0] = (short)f2bf(lo.x); af[j][1] = (short)f2bf(lo.y);
            af[j][2] = (short)f2bf(lo.z); af[j][3] = (short)f2bf(lo.w);
            af[j][4] = (short)f2bf(hi.x); af[j][5] = (short)f2bf(hi.y);
            af[j][6] = (short)f2bf(hi.z); af[j][7] = (short)f2bf(hi.w);
        }
        #pragma unroll
        for (int f = 0; f < 4; f++) {
            int nl = wn * 64 + f * 16 + fr;
            int lb = (nl * 512 + (kk * 32 + quad * 8) * 2) ^ ((nl & 7) << 4);
            bf16x8 bfr = *(const bf16x8*)(smem + lb);
            #pragma unroll
            for (int j = 0; j < 4; j++)
                acc[j][f] = __builtin_amdgcn_mfma_f32_16x16x32_bf16(bfr, af[j], acc[j][f], 0, 0, 0);
        }
    }
    // lane holds D[row = m0+wm*64+j*16+fr][col = wn*64+f*16+quad*4+r]

    // fused el/er (head wn)
    #pragma unroll
    for (int j = 0; j < 4; j++) {
        float pl = 0.f, pr = 0.f;
        #pragma unroll
        for (int f = 0; f < 4; f++) {
            float4 a4 = *(const float4*)(al + wn * 64 + f * 16 + quad * 4);
            float4 b4 = *(const float4*)(ar + wn * 64 + f * 16 + quad * 4);
            pl += acc[j][f][0] * a4.x + acc[j][f][1] * a4.y + acc[j][f][2] * a4.z + acc[j][f][3] * a4.w;
            pr += acc[j][f][0] * b4.x + acc[j][f][1] * b4.y + acc[j][f][2] * b4.z + acc[j][f][3] * b4.w;
        }
        pl += __shfl_xor(pl, 16); pl += __shfl_xor(pl, 32);
        pr += __shfl_xor(pr, 16); pr += __shfl_xor(pr, 32);
        if (quad == 0 && gm[j] < M) {
            el[gm[j] * NH + wn] = pl;
            er[gm[j] * NH + wn] = pr;
        }
    }

    // direct bf16 stores
    #pragma unroll
    for (int j = 0; j < 4; j++) {
        if (gm[j] < M) {
            unsigned short* dp = ftb + (size_t)gm[j] * HD + wn * 64 + quad * 4;
            #pragma unroll
            for (int f = 0; f < 4; f++) {
                ushort4 pk;
                pk.x = f2bf(acc[j][f][0]);
                pk.y = f2bf(acc[j][f][1]);
                pk.z = f2bf(acc[j][f][2]);
                pk.w = f2bf(acc[j][f][3]);
                *(ushort4*)(dp + f * 16) = pk;
            }
        }
    }
}

// ---------------- CSR scan (scan1 merges the 8 histogram copies) ----------------
__global__ __launch_bounds__(512) void k_scan1(const int* __restrict__ counts8,
                                               int* __restrict__ counts,
                                               int* __restrict__ incl,
                                               int* __restrict__ bsum, int N) {
    __shared__ int sm[512];
    int i = blockIdx.x * 512 + threadIdx.x;
    int v = 0;
    if (i < N) {
        #pragma unroll
        for (int c = 0; c < 8; c++) v += counts8[c * N_NODES + i];
        counts[i] = v;
    }
    sm[threadIdx.x] = v;
    __syncthreads();
    for (int off = 1; off < 512; off <<= 1) {
        int t = (threadIdx.x >= off) ? sm[threadIdx.x - off] : 0;
        __syncthreads();
        sm[threadIdx.x] += t;
        __syncthreads();
    }
    if (i < N) incl[i] = sm[threadIdx.x];
    if (threadIdx.x == 511) bsum[blockIdx.x] = sm[511];
}

__global__ __launch_bounds__(128) void k_scan2(int* __restrict__ bsum, int nb) {
    __shared__ int sm[128];
    int v = (threadIdx.x < nb) ? bsum[threadIdx.x] : 0;
    sm[threadIdx.x] = v;
    __syncthreads();
    for (int off = 1; off < 128; off <<= 1) {
        int t = (threadIdx.x >= off) ? sm[threadIdx.x - off] : 0;
        __syncthreads();
        sm[threadIdx.x] += t;
        __syncthreads();
    }
    if (threadIdx.x < nb) bsum[threadIdx.x] = sm[threadIdx.x] - v;  // exclusive
}

__global__ __launch_bounds__(256) void k_scan3(const int* __restrict__ counts,
                                               const int* __restrict__ incl,
                                               const int* __restrict__ bsum,
                                               int* __restrict__ offs,
                                               int* __restrict__ cursor, int N) {
    int i = blockIdx.x * blockDim.x + threadIdx.x;
    if (i < N) {
        int o = incl[i] - counts[i] + bsum[i >> 9];
        offs[i] = o;
        cursor[i] = o;
    }
}

// ---------------- scatter: CSR adjacency (src ids only) ----------------
__global__ __launch_bounds__(256) void k_scatter(const int* __restrict__ src,
                                                 const int* __restrict__ dst,
                                                 int* __restrict__ cursor,
                                                 int* __restrict__ esrc) {
    int e = blockIdx.x * blockDim.x + threadIdx.x;
    if (e < N_EDGES) {
        int p = atomicAdd(&cursor[dst[e]], 1);
        esrc[p] = src[e];
    }
}

// ---------------- Aggregation: one wave per dst node, 2 edges in flight ----------
// pass 1: exp-weights (computed once, lane-parallel) -> wave-private LDS slab.
// pass 2: 32 lanes x 16 B per edge, lanes 32-63 take the odd edge -> 2x fewer
// serial iterations, 8 gathers in flight with unroll 4. Merge via shfl_xor(32).
__global__ __launch_bounds__(256) void k_agg(const unsigned short* __restrict__ ftb,
                                             const float* __restrict__ el,
                                             const float* __restrict__ er,
                                             const int* __restrict__ offs,
                                             const int* __restrict__ counts,
                                             const int* __restrict__ esrc,
                                             float* __restrict__ out, int N) {
    __shared__ float4 wcache[4][256];           // 16 KB: 4 waves x 256 edges
    const int wv = threadIdx.x >> 6;
    int wid = (blockIdx.x * 256 + threadIdx.x) >> 6;
    const int lane = threadIdx.x & 63;
    if (wid >= N) return;
    const int deg = counts[wid];
    const int start = offs[wid];
    const int half = lane >> 5;                 // which edge of the pair
    const int l5 = lane & 31;                   // 16-B column slot
    const int hsel = l5 >> 3;                   // head of my 8 columns
    float4* wc = &wcache[wv][0];
    const float* wf = (const float*)wc;

    float4 r4 = ((const float4*)er)[wid];       // node-uniform

    float sx = 0.f, sy = 0.f, sz = 0.f, sw = 0.f;
    float acc[8] = {0.f, 0.f, 0.f, 0.f, 0.f, 0.f, 0.f, 0.f};

    for (int c0 = 0; c0 < deg; c0 += 256) {
        int clen = min(deg - c0, 256);
        // pass 1: weights into LDS + denominator partials
        for (int i = lane; i < clen; i += 64) {
            int sv = esrc[start + c0 + i];
            float4 l4 = ((const float4*)el)[sv];
            float x;
            x = l4.x + r4.x; x = (x > 0.f) ? x : ALPHA * x; float w0 = __expf(x);
            x = l4.y + r4.y; x = (x > 0.f) ? x : ALPHA * x; float w1 = __expf(x);
            x = l4.z + r4.z; x = (x > 0.f) ? x : ALPHA * x; float w2 = __expf(x);
            x = l4.w + r4.w; x = (x > 0.f) ? x : ALPHA * x; float w3 = __expf(x);
            wc[i] = make_float4(w0, w1, w2, w3);
            sx += w0; sy += w1; sz += w2; sw += w3;
        }
        // pass 2: two edges per iteration (wave-private LDS, no barrier)
        int nit = clen >> 1;
        #pragma unroll 4
        for (int t = 0; t < nit; t++) {
            int idx = 2 * t + half;
            int sv = esrc[start + c0 + idx];          // L1-hot
            float we = wf[idx * 4 + hsel];            // broadcast ds_read
            bf16x8 fv = *(const bf16x8*)(ftb + (size_t)sv * HD + l5 * 8);
            #pragma unroll
            for (int k = 0; k < 8; k++)
                acc[k] = fmaf(we, bf2f((unsigned short)fv[k]), acc[k]);
        }
        if (clen & 1) {
            int idx = clen - 1;
            if (half == 0) {
                int sv = esrc[start + c0 + idx];
                float we = wf[idx * 4 + hsel];
                bf16x8 fv = *(const bf16x8*)(ftb + (size_t)sv * HD + l5 * 8);
                #pragma unroll
                for (int k = 0; k < 8; k++)
                    acc[k] = fmaf(we, bf2f((unsigned short)fv[k]), acc[k]);
            }
        }
    }

    // denominators
    #pragma unroll
    for (int off = 1; off < 64; off <<= 1) {
        sx += __shfl_xor(sx, off);
        sy += __shfl_xor(sy, off);
        sz += __shfl_xor(sz, off);
        sw += __shfl_xor(sw, off);
    }
    float dq = (hsel == 0) ? sx : (hsel == 1) ? sy : (hsel == 2) ? sz : sw;
    float invd = (deg > 0 && dq > 0.f) ? 1.f / dq : 0.f;

    // merge the two edge-halves
    #pragma unroll
    for (int k = 0; k < 8; k++) acc[k] += __shfl_xor(acc[k], 32);

    f32x4 o;
    if (half) { o[0] = acc[4]; o[1] = acc[5]; o[2] = acc[6]; o[3] = acc[7]; }
    else      { o[0] = acc[0]; o[1] = acc[1]; o[2] = acc[2]; o[3] = acc[3]; }
    o[0] *= invd; o[1] *= invd; o[2] *= invd; o[3] *= invd;
    __builtin_nontemporal_store(o, (f32x4*)out + (size_t)wid * 64 + l5 * 2 + half);
}

// ---------------- launch ----------------
extern "C" void kernel_launch(void* const* d_in, const int* in_sizes, int n_in,
                              void* d_out, int out_size, void* d_ws, size_t ws_size,
                              hipStream_t stream) {
    const float* feat = (const float*)d_in[0];
    const float* fc_w = (const float*)d_in[1];
    const float* attn_l = (const float*)d_in[2];
    const float* attn_r = (const float*)d_in[3];
    const int* src = (const int*)d_in[4];
    const int* dst = (const int*)d_in[5];
    float* out = (float*)d_out;

    char* w = (char*)d_ws;
    unsigned short* ftb = (unsigned short*)w;  w += (size_t)N_NODES * HD * 2;      // 25.6 MB
    unsigned short* Bt = (unsigned short*)w;   w += (size_t)IN_F * HD * 2;         // 128 KB
    float* el = (float*)w;       w += (size_t)N_NODES * NH * 4;                    // 800 KB
    float* er = (float*)w;       w += (size_t)N_NODES * NH * 4;                    // 800 KB
    int* counts8 = (int*)w;      w += (size_t)8 * N_NODES * 4;                     // 1.6 MB
    int* counts = (int*)w;       w += (size_t)N_NODES * 4;
    int* incl = (int*)w;         w += (size_t)N_NODES * 4;
    int* offs = (int*)w;         w += (size_t)N_NODES * 4;
    int* cursor = (int*)w;       w += (size_t)N_NODES * 4;
    int* bsum = (int*)w;         w += 1024;
    int* esrc = (int*)w;         w += (size_t)N_EDGES * 4;                          // 3.2 MB

    (void)hipMemsetAsync(counts8, 0, (size_t)8 * N_NODES * 4, stream);

    int eblocks = (N_EDGES + 255) / 256;
    k_prep<<<256 + eblocks, 256, 0, stream>>>(fc_w, Bt, dst, counts8);

    k_gemm<<<(N_NODES + 127) / 128, 512, 0, stream>>>(feat, Bt, ftb, el, er,
                                                      attn_l, attn_r, N_NODES);

    int nsb = (N_NODES + 511) / 512;
    k_scan1<<<nsb, 512, 0, stream>>>(counts8, counts, incl, bsum, N_NODES);
    k_scan2<<<1, 128, 0, stream>>>(bsum, nsb);
    k_scan3<<<(N_NODES + 255) / 256, 256, 0, stream>>>(counts, incl, bsum, offs, cursor, N_NODES);
    k_scatter<<<eblocks, 256, 0, stream>>>(src, dst, cursor, esrc);

    int agg_blocks = (N_NODES * 64 + 255) / 256;
    k_agg<<<agg_blocks, 256, 0, stream>>>(ftb, el, er, offs, counts, esrc, out, N_NODES);
}

// Round 9
// 199.595 us; speedup vs baseline: 1.9092x; 1.0334x over previous
//
#include <hip/hip_runtime.h>
#include <hip/hip_bf16.h>
#include <hip/hip_fp16.h>

#define N_NODES 50000
#define N_EDGES 800000
#define IN_F 256
#define NH 4
#define DH 64
#define HD 256
#define ALPHA 0.2f

typedef short bf16x8 __attribute__((ext_vector_type(8)));
typedef float f32x4 __attribute__((ext_vector_type(4)));

__device__ __forceinline__ unsigned short f2bf(float f) {
    unsigned u = __float_as_uint(f);
    u = (u + 0x7FFFu + ((u >> 16) & 1u)) >> 16;   // RNE
    return (unsigned short)u;
}
__device__ __forceinline__ float bf2f(unsigned short h) {
    return __uint_as_float(((unsigned)h) << 16);
}

// ---------------- fused prep: Bt transpose-convert + dst histogram (8 copies) -------
__global__ __launch_bounds__(256) void k_prep(const float* __restrict__ fw,
                                              unsigned short* __restrict__ Bt,
                                              const int* __restrict__ dst,
                                              int* __restrict__ counts8) {
    if (blockIdx.x < 256) {
        int n = blockIdx.x;            // 0..255
        int k = threadIdx.x;           // 0..255
        Bt[n * 256 + k] = f2bf(fw[k * 256 + n]);
    } else {
        int b = blockIdx.x - 256;
        int e = b * 256 + threadIdx.x;
        if (e < N_EDGES) atomicAdd(&counts8[(b & 7) * N_NODES + dst[e]], 1);
    }
}

// ---------------- GEMM: fth = f16( feat @ fc_w ) + fused el/er ----------------
// BM=128, BN=256 (full), 512 threads = 8 waves (2M x 4N); B staged once in LDS
// (XOR-swizzled). Swapped-operand MFMA -> lane&15 = output ROW -> direct packed
// f16 stores + in-register el/er. One barrier total.
__global__ __launch_bounds__(512) void k_gemm(const float* __restrict__ A,
                                              const unsigned short* __restrict__ Bt,
                                              unsigned short* __restrict__ fth,
                                              float* __restrict__ el,
                                              float* __restrict__ er,
                                              const float* __restrict__ al,
                                              const float* __restrict__ ar, int M) {
    __shared__ __align__(16) char smem[131072];   // B-tile 256x256 bf16, swizzled
    const int tid = threadIdx.x;
    const int m0 = blockIdx.x * 128;

    #pragma unroll
    for (int c = 0; c < 16; c++) {
        int o = c * 8192 + tid * 16;            // byte offset
        bf16x8 v = *(const bf16x8*)((const char*)Bt + o);
        int nl = o >> 9;
        int lb = o ^ ((nl & 7) << 4);
        *(bf16x8*)(smem + lb) = v;
    }
    __syncthreads();

    const int w = tid >> 6, lane = tid & 63;
    const int wm = w >> 2, wn = w & 3;          // 2 x 4; wave's 64-col slice = head wn
    const int fr = lane & 15, quad = lane >> 4;

    const float* arow[4];
    int gm[4];
    #pragma unroll
    for (int j = 0; j < 4; j++) {
        gm[j] = m0 + wm * 64 + j * 16 + fr;
        int cr = gm[j] < M ? gm[j] : (M - 1);
        arow[j] = A + (size_t)cr * IN_F;
    }

    f32x4 acc[4][4];
    #pragma unroll
    for (int j = 0; j < 4; j++)
        #pragma unroll
        for (int f = 0; f < 4; f++) acc[j][f] = (f32x4){0.f, 0.f, 0.f, 0.f};

    #pragma unroll
    for (int kk = 0; kk < 8; kk++) {
        bf16x8 af[4];
        #pragma unroll
        for (int j = 0; j < 4; j++) {
            float4 lo = *(const float4*)(arow[j] + kk * 32 + quad * 8);
            float4 hi = *(const float4*)(arow[j] + kk * 32 + quad * 8 + 4);
            af[j][0] = (short)f2bf(lo.x); af[j][1] = (short)f2bf(lo.y);
            af[j][2] = (short)f2bf(lo.z); af[j][3] = (short)f2bf(lo.w);
            af[j][4] = (short)f2bf(hi.x); af[j][5] = (short)f2bf(hi.y);
            af[j][6] = (short)f2bf(hi.z); af[j][7] = (short)f2bf(hi.w);
        }
        #pragma unroll
        for (int f = 0; f < 4; f++) {
            int nl = wn * 64 + f * 16 + fr;
            int lb = (nl * 512 + (kk * 32 + quad * 8) * 2) ^ ((nl & 7) << 4);
            bf16x8 bfr = *(const bf16x8*)(smem + lb);
            #pragma unroll
            for (int j = 0; j < 4; j++)
                acc[j][f] = __builtin_amdgcn_mfma_f32_16x16x32_bf16(bfr, af[j], acc[j][f], 0, 0, 0);
        }
    }
    // lane holds D[row = m0+wm*64+j*16+fr][col = wn*64+f*16+quad*4+r]

    // fused el/er (head wn)
    #pragma unroll
    for (int j = 0; j < 4; j++) {
        float pl = 0.f, pr = 0.f;
        #pragma unroll
        for (int f = 0; f < 4; f++) {
            float4 a4 = *(const float4*)(al + wn * 64 + f * 16 + quad * 4);
            float4 b4 = *(const float4*)(ar + wn * 64 + f * 16 + quad * 4);
            pl += acc[j][f][0] * a4.x + acc[j][f][1] * a4.y + acc[j][f][2] * a4.z + acc[j][f][3] * a4.w;
            pr += acc[j][f][0] * b4.x + acc[j][f][1] * b4.y + acc[j][f][2] * b4.z + acc[j][f][3] * b4.w;
        }
        pl += __shfl_xor(pl, 16); pl += __shfl_xor(pl, 32);
        pr += __shfl_xor(pr, 16); pr += __shfl_xor(pr, 32);
        if (quad == 0 && gm[j] < M) {
            el[gm[j] * NH + wn] = pl;
            er[gm[j] * NH + wn] = pr;
        }
    }

    // direct f16 stores
    #pragma unroll
    for (int j = 0; j < 4; j++) {
        if (gm[j] < M) {
            unsigned short* dp = fth + (size_t)gm[j] * HD + wn * 64 + quad * 4;
            #pragma unroll
            for (int f = 0; f < 4; f++) {
                ushort4 pk;
                pk.x = __half_as_ushort(__float2half(acc[j][f][0]));
                pk.y = __half_as_ushort(__float2half(acc[j][f][1]));
                pk.z = __half_as_ushort(__float2half(acc[j][f][2]));
                pk.w = __half_as_ushort(__float2half(acc[j][f][3]));
                *(ushort4*)(dp + f * 16) = pk;
            }
        }
    }
}

// ---------------- CSR scan (scan1 merges the 8 histogram copies) ----------------
__global__ __launch_bounds__(512) void k_scan1(const int* __restrict__ counts8,
                                               int* __restrict__ counts,
                                               int* __restrict__ incl,
                                               int* __restrict__ bsum, int N) {
    __shared__ int sm[512];
    int i = blockIdx.x * 512 + threadIdx.x;
    int v = 0;
    if (i < N) {
        #pragma unroll
        for (int c = 0; c < 8; c++) v += counts8[c * N_NODES + i];
        counts[i] = v;
    }
    sm[threadIdx.x] = v;
    __syncthreads();
    for (int off = 1; off < 512; off <<= 1) {
        int t = (threadIdx.x >= off) ? sm[threadIdx.x - off] : 0;
        __syncthreads();
        sm[threadIdx.x] += t;
        __syncthreads();
    }
    if (i < N) incl[i] = sm[threadIdx.x];
    if (threadIdx.x == 511) bsum[blockIdx.x] = sm[511];
}

// scan3 with inlined bsum prefix (kills the scan2 dispatch): block b needs
// sum(bsum[0 .. (b>>1)-1]) since 256-thread blocks map 2:1 onto 512-wide scan1 blocks.
__global__ __launch_bounds__(256) void k_scan3(const int* __restrict__ counts,
                                               const int* __restrict__ incl,
                                               const int* __restrict__ bsum,
                                               int* __restrict__ offs,
                                               int* __restrict__ cursor, int N) {
    __shared__ int sprefix;
    int nb = blockIdx.x >> 1;
    if (threadIdx.x < 64) {
        int v = 0;
        for (int j = threadIdx.x; j < nb; j += 64) v += bsum[j];
        #pragma unroll
        for (int off = 1; off < 64; off <<= 1) v += __shfl_xor(v, off);
        if (threadIdx.x == 0) sprefix = v;
    }
    __syncthreads();
    int i = blockIdx.x * 256 + threadIdx.x;
    if (i < N) {
        int o = incl[i] - counts[i] + sprefix;
        offs[i] = o;
        cursor[i] = o;
    }
}

// ---------------- scatter: CSR adjacency (src ids only) ----------------
__global__ __launch_bounds__(256) void k_scatter(const int* __restrict__ src,
                                                 const int* __restrict__ dst,
                                                 int* __restrict__ cursor,
                                                 int* __restrict__ esrc) {
    int e = blockIdx.x * blockDim.x + threadIdx.x;
    if (e < N_EDGES) {
        int p = atomicAdd(&cursor[dst[e]], 1);
        esrc[p] = src[e];
    }
}

// ---------------- Aggregation: one wave per dst node, f16 pk_fma ----------------
// pass 1: exp-weights once (lane-parallel) -> wave-private LDS slab + denominators.
// reduce denominators, then pass 2 accumulates PRE-NORMALIZED weights (<=1) with
// v_pk_fma_f16: 8 cols/lane = 2 packed FMAs. f16 accumulator stays ~|ft| <= 4.
__global__ __launch_bounds__(256) void k_agg(const unsigned short* __restrict__ fth,
                                             const float* __restrict__ el,
                                             const float* __restrict__ er,
                                             const int* __restrict__ offs,
                                             const int* __restrict__ counts,
                                             const int* __restrict__ esrc,
                                             float* __restrict__ out, int N) {
    __shared__ float4 wcache[4][256];           // 16 KB: 4 waves x 256 edges
    const int wv = threadIdx.x >> 6;
    int wid = (blockIdx.x * 256 + threadIdx.x) >> 6;
    const int lane = threadIdx.x & 63;
    if (wid >= N) return;
    const int deg = counts[wid];
    const int start = offs[wid];
    const int quad = lane >> 4;                 // head of my 4 cols
    float4* wc = &wcache[wv][0];
    const float* wf = (const float*)wc;

    float4 r4 = ((const float4*)er)[wid];       // node-uniform

    if (deg <= 256) {
        // pass 1: weights into LDS + denominator partials
        float sx = 0.f, sy = 0.f, sz = 0.f, sw = 0.f;
        for (int i = lane; i < deg; i += 64) {
            int sv = esrc[start + i];
            float4 l4 = ((const float4*)el)[sv];
            float x;
            x = l4.x + r4.x; x = (x > 0.f) ? x : ALPHA * x; float w0 = __expf(x);
            x = l4.y + r4.y; x = (x > 0.f) ? x : ALPHA * x; float w1 = __expf(x);
            x = l4.z + r4.z; x = (x > 0.f) ? x : ALPHA * x; float w2 = __expf(x);
            x = l4.w + r4.w; x = (x > 0.f) ? x : ALPHA * x; float w3 = __expf(x);
            wc[i] = make_float4(w0, w1, w2, w3);
            sx += w0; sy += w1; sz += w2; sw += w3;
        }
        #pragma unroll
        for (int off = 1; off < 64; off <<= 1) {
            sx += __shfl_xor(sx, off);
            sy += __shfl_xor(sy, off);
            sz += __shfl_xor(sz, off);
            sw += __shfl_xor(sw, off);
        }
        float dq = (quad == 0) ? sx : (quad == 1) ? sy : (quad == 2) ? sz : sw;
        float invd = (deg > 0 && dq > 0.f) ? 1.f / dq : 0.f;

        // pass 2: normalized-weight f16 packed FMA; lane owns 4 cols (head = quad)
        __half2 acc0 = __float2half2_rn(0.f);
        __half2 acc1 = __float2half2_rn(0.f);
        #pragma unroll 4
        for (int i = 0; i < deg; i++) {
            int sv = esrc[start + i];                 // L1-hot from pass 1
            float wn_ = wf[i * 4 + quad] * invd;      // broadcast ds_read, <=1
            __half2 w2 = __float2half2_rn(wn_);
            float2 raw = ((const float2*)fth)[(size_t)sv * 64 + lane];
            __half2 h0 = *reinterpret_cast<const __half2*>(&raw.x);
            __half2 h1 = *reinterpret_cast<const __half2*>(&raw.y);
            acc0 = __hfma2(w2, h0, acc0);
            acc1 = __hfma2(w2, h1, acc1);
        }
        f32x4 o;
        o[0] = __low2float(acc0); o[1] = __high2float(acc0);
        o[2] = __low2float(acc1); o[3] = __high2float(acc1);
        __builtin_nontemporal_store(o, (f32x4*)out + (size_t)wid * 64 + lane);
    } else {
        // fallback (deg > 256): f32 path, no cache — correctness only
        float erq = (quad == 0) ? r4.x : (quad == 1) ? r4.y : (quad == 2) ? r4.z : r4.w;
        float sx = 0.f, sy = 0.f, sz = 0.f, sw = 0.f;
        for (int i = lane; i < deg; i += 64) {
            int sv = esrc[start + i];
            float4 l4 = ((const float4*)el)[sv];
            float x;
            x = l4.x + r4.x; x = (x > 0.f) ? x : ALPHA * x; sx += __expf(x);
            x = l4.y + r4.y; x = (x > 0.f) ? x : ALPHA * x; sy += __expf(x);
            x = l4.z + r4.z; x = (x > 0.f) ? x : ALPHA * x; sz += __expf(x);
            x = l4.w + r4.w; x = (x > 0.f) ? x : ALPHA * x; sw += __expf(x);
        }
        #pragma unroll
        for (int off = 1; off < 64; off <<= 1) {
            sx += __shfl_xor(sx, off);
            sy += __shfl_xor(sy, off);
            sz += __shfl_xor(sz, off);
            sw += __shfl_xor(sw, off);
        }
        float dq = (quad == 0) ? sx : (quad == 1) ? sy : (quad == 2) ? sz : sw;
        float invd = (dq > 0.f) ? 1.f / dq : 0.f;
        float a0 = 0.f, a1 = 0.f, a2 = 0.f, a3 = 0.f;
        for (int i = 0; i < deg; i++) {
            int sv = esrc[start + i];
            float x = el[sv * NH + quad] + erq;
            x = (x > 0.f) ? x : ALPHA * x;
            float we = __expf(x);
            float2 raw = ((const float2*)fth)[(size_t)sv * 64 + lane];
            __half2 h0 = *reinterpret_cast<const __half2*>(&raw.x);
            __half2 h1 = *reinterpret_cast<const __half2*>(&raw.y);
            a0 = fmaf(we, __low2float(h0), a0);
            a1 = fmaf(we, __high2float(h0), a1);
            a2 = fmaf(we, __low2float(h1), a2);
            a3 = fmaf(we, __high2float(h1), a3);
        }
        f32x4 o;
        o[0] = a0 * invd; o[1] = a1 * invd; o[2] = a2 * invd; o[3] = a3 * invd;
        __builtin_nontemporal_store(o, (f32x4*)out + (size_t)wid * 64 + lane);
    }
}

// ---------------- launch ----------------
extern "C" void kernel_launch(void* const* d_in, const int* in_sizes, int n_in,
                              void* d_out, int out_size, void* d_ws, size_t ws_size,
                              hipStream_t stream) {
    const float* feat = (const float*)d_in[0];
    const float* fc_w = (const float*)d_in[1];
    const float* attn_l = (const float*)d_in[2];
    const float* attn_r = (const float*)d_in[3];
    const int* src = (const int*)d_in[4];
    const int* dst = (const int*)d_in[5];
    float* out = (float*)d_out;

    char* w = (char*)d_ws;
    unsigned short* fth = (unsigned short*)w;  w += (size_t)N_NODES * HD * 2;      // 25.6 MB (f16)
    unsigned short* Bt = (unsigned short*)w;   w += (size_t)IN_F * HD * 2;         // 128 KB (bf16)
    float* el = (float*)w;       w += (size_t)N_NODES * NH * 4;                    // 800 KB
    float* er = (float*)w;       w += (size_t)N_NODES * NH * 4;                    // 800 KB
    int* counts8 = (int*)w;      w += (size_t)8 * N_NODES * 4;                     // 1.6 MB
    int* counts = (int*)w;       w += (size_t)N_NODES * 4;
    int* incl = (int*)w;         w += (size_t)N_NODES * 4;
    int* offs = (int*)w;         w += (size_t)N_NODES * 4;
    int* cursor = (int*)w;       w += (size_t)N_NODES * 4;
    int* bsum = (int*)w;         w += 1024;
    int* esrc = (int*)w;         w += (size_t)N_EDGES * 4;                          // 3.2 MB

    (void)hipMemsetAsync(counts8, 0, (size_t)8 * N_NODES * 4, stream);

    int eblocks = (N_EDGES + 255) / 256;
    k_prep<<<256 + eblocks, 256, 0, stream>>>(fc_w, Bt, dst, counts8);

    k_gemm<<<(N_NODES + 127) / 128, 512, 0, stream>>>(feat, Bt, fth, el, er,
                                                      attn_l, attn_r, N_NODES);

    int nsb = (N_NODES + 511) / 512;
    k_scan1<<<nsb, 512, 0, stream>>>(counts8, counts, incl, bsum, N_NODES);
    k_scan3<<<(N_NODES + 255) / 256, 256, 0, stream>>>(counts, incl, bsum, offs, cursor, N_NODES);
    k_scatter<<<eblocks, 256, 0, stream>>>(src, dst, cursor, esrc);

    int agg_blocks = (N_NODES * 64 + 255) / 256;
    k_agg<<<agg_blocks, 256, 0, stream>>>(fth, el, er, offs, counts, esrc, out, N_NODES);
}